// Round 4
// baseline (5461.775 us; speedup 1.0000x reference)
//
#include <hip/hip_runtime.h>
#include <hip/hip_bf16.h>

// Persistent LSTM, round 7. B=128,T=1024,V=256,H=512,G=2048.
// 8 batch groups (16 rows) x 8 WGs (64 h-elems = 256 gate rows) = 64 WGs, 256 thr.
// Protocol: TAG-IN-DATA. hbuf chunks are 16B [h0h1|tag|h2h3|tag] (tag duplicated
// per 8B half). Producer: one dwordx4 sc1 store per thread, NO drain, NO flag.
// Consumer: polls exactly the 8 chunks it stages (dwordx4 sc1), reloading only
// stale ones; first fresh read IS the data. Backpressure invariant unchanged:
// writing slot (t+1)&1 requires all tags >= t, which proves every peer finished
// step t-1 and already read that slot. Barriers: 3 -> 2 per step (hazard audit:
// stage-vs-MFMA separated by post-MFMA barrier; gates_s by post-stage barrier).
// All sync primitives are the r3/r5-proven ones (sc1 loads/stores); no sc0.

#define TT 1024
#define BB 128
#define HH 512
#define VV 256
#define NGP 8   // batch groups
#define GM 16   // batch rows per group
#define NWG 8   // WGs per group
#define NE 64   // h-elems per WG

typedef __attribute__((ext_vector_type(8))) short short8;
typedef __attribute__((ext_vector_type(4))) float f32x4;
typedef __attribute__((ext_vector_type(4))) unsigned u32x4;
typedef unsigned long long u64;
typedef unsigned short u16;
typedef unsigned char u8;
typedef unsigned u32;

__device__ __forceinline__ u16 f2bf(float f) {
  __hip_bfloat16 h = __float2bfloat16(f);
  return *reinterpret_cast<u16*>(&h);
}
__device__ __forceinline__ float sigm(float x) { return 1.0f / (1.0f + __expf(-x)); }
__device__ __forceinline__ float tanh_(float x) { return 1.0f - 2.0f / (1.0f + __expf(2.0f * x)); }

__global__ void lstm_init(const int* __restrict__ x, u8* __restrict__ x_t,
                          u32* __restrict__ hbuf) {
  int idx = blockIdx.x * 256 + threadIdx.x;   // 0..131071
  int t = idx >> 7, b = idx & 127;
  x_t[idx] = (u8)x[b * TT + t];               // x_t[t][b], V=256 fits u8
  hbuf[idx] = 0u;                             // zero BOTH slots (512KB): h=0, tags=0
}

__launch_bounds__(256, 1)
__global__ void lstm_persist(const u8* __restrict__ x_t, const int* __restrict__ x_len,
                             const float* __restrict__ W_ih, const float* __restrict__ W_hh,
                             const float* __restrict__ b_ih, const float* __restrict__ b_hh,
                             float* __restrict__ out,
                             u32* __restrict__ hbuf) { // [2][128 rows][128 chunks][16B]
  const int tid = threadIdx.x;
  const int wave = tid >> 6, lane = tid & 63;
  const int nn = lane & 15, quad = lane >> 4;
  const int g = blockIdx.x >> 3, ig = blockIdx.x & 7;   // r5-proven mapping

  __shared__ u16 hA[GM * 520];          // staged h slab 16x512, stride 520
  __shared__ float gates_s[GM * 260];   // [16 b][256 gate cols], stride 260
  __shared__ int gmax_s;

  // ---- persistent W_hh fragments: wave=q, subtile s, col nn ----
  short8 bw[4][16];
#pragma unroll
  for (int s = 0; s < 4; s++) {
    const float* src = W_hh + (size_t)(wave * HH + ig * NE + s * 16 + nn) * HH + quad * 8;
#pragma unroll
    for (int kt = 0; kt < 16; kt++) {
      const float* p = src + kt * 32;
      short8 v;
#pragma unroll
      for (int j = 0; j < 8; j++) v[j] = (short)f2bf(p[j]);
      bw[s][kt] = v;
    }
  }

  // ---- cell mapping: thread -> (bc = tid>>4, 4 elems at e4=(tid&15)*4) ----
  const int bc = tid >> 4, e4 = (tid & 15) * 4;
  const int bglob = g * GM + bc;
  const int xl = x_len[bglob];
  float bias[4][4];
#pragma unroll
  for (int q = 0; q < 4; q++)
#pragma unroll
    for (int j = 0; j < 4; j++) {
      int grow = q * HH + ig * NE + e4 + j;
      bias[q][j] = b_ih[grow] + b_hh[grow];
    }
  float cst[4] = {0.f, 0.f, 0.f, 0.f}, hst[4] = {0.f, 0.f, 0.f, 0.f};

  if (tid == 0) gmax_s = 1;
  __syncthreads();
  if ((tid & 15) == 0) atomicMax(&gmax_s, xl);

  // consumer map: thread (srow=tid>>4, sc16=tid&15) stages row g*GM+srow,
  // chunks k*16+sc16 (k=0..7). Per k: 16 threads read 16 consecutive chunks
  // = 256B coalesced; producer of chunk col c is WG ig=c/16, so the 8 k's
  // validate all 8 producers. ds_write_b64 at elem col k*64+sc16*4: each
  // srow-phase covers all 32 banks exactly once -> conflict-free.
  const int srow = tid >> 4, sc16 = tid & 15;
  const u64 hb = (u64)hbuf;
  const u64 crow_off = (u64)((size_t)(g * GM + srow) * 128 * 16);

  // producer map: chunk col = ig*16 + (tid&15), row bglob
  const u64 pub_off = (u64)(((size_t)bglob * 128 + ig * 16 + (tid & 15)) * 16);

  __syncthreads();
  const int gmax = gmax_s;

  for (int t = 0; t < gmax; ++t) {
    const int slot = t & 1;

    // prefetchable per-step inputs (fly during poll); bias folded in
    const int xv = (int)x_t[t * BB + bglob];
    float w[4][4];
#pragma unroll
    for (int q = 0; q < 4; q++)
#pragma unroll
      for (int j = 0; j < 4; j++)
        w[q][j] = W_ih[(size_t)(q * HH + ig * NE + e4 + j) * VV + xv] + bias[q][j];

    // 1. poll+stage: self-validating chunk reads (tag in both 8B halves)
    {
      const u64 rb = hb + (u64)((size_t)slot * BB * 128 * 16) + crow_off;
      u32x4 vv[8];
      unsigned need = 0xFFu;
      const unsigned tt = (unsigned)t;
      while (need) {
#pragma unroll
        for (int k = 0; k < 8; ++k)
          if (need & (1u << k)) {
            asm volatile("global_load_dwordx4 %0, %1, off sc1"
                         : "=v"(vv[k])
                         : "v"(rb + (u64)((k * 16 + sc16) * 16))
                         : "memory");
          }
        asm volatile("s_waitcnt vmcnt(0)" ::: "memory");
#pragma unroll
        for (int k = 0; k < 8; ++k)
          if (vv[k][1] >= tt && vv[k][3] >= tt) need &= ~(1u << k);
      }
#pragma unroll
      for (int k = 0; k < 8; ++k) {
        u64 hw = (u64)vv[k][0] | ((u64)vv[k][2] << 32);
        *reinterpret_cast<u64*>(&hA[srow * 520 + k * 64 + sc16 * 4]) = hw;
      }
    }
    __syncthreads();

    // 2. gates = h @ W_hh_slice^T : M=16, N=64 (4 subtiles), K=512 per wave
    {
      f32x4 acc[4] = {{0,0,0,0},{0,0,0,0},{0,0,0,0},{0,0,0,0}};
      const u16* ap = hA + nn * 520 + quad * 8;
#pragma unroll
      for (int kt = 0; kt < 16; kt++) {
        short8 a = *(const short8*)(ap + kt * 32);
#pragma unroll
        for (int s = 0; s < 4; s++)
          acc[s] = __builtin_amdgcn_mfma_f32_16x16x32_bf16(a, bw[s][kt], acc[s], 0, 0, 0);
      }
#pragma unroll
      for (int s = 0; s < 4; s++)
#pragma unroll
        for (int r = 0; r < 4; r++)
          gates_s[(quad * 4 + r) * 260 + wave * NE + s * 16 + nn] = acc[s][r];
    }
    __syncthreads();

    // 3. cell update + direct tagged publish (no drain, no flag, no barrier)
    {
      f32x4 G0 = *(const f32x4*)&gates_s[bc * 260 + 0 * NE + e4];
      f32x4 G1 = *(const f32x4*)&gates_s[bc * 260 + 1 * NE + e4];
      f32x4 G2 = *(const f32x4*)&gates_s[bc * 260 + 2 * NE + e4];
      f32x4 G3 = *(const f32x4*)&gates_s[bc * 260 + 3 * NE + e4];
      const bool act = (t < xl);
      f32x4 outv;
#pragma unroll
      for (int j = 0; j < 4; j++) {
        float gi = G0[j] + w[0][j];
        float gf = G1[j] + w[1][j];
        float gg = G2[j] + w[2][j];
        float go = G3[j] + w[3][j];
        float iv = sigm(gi), fv = sigm(gf), gv = tanh_(gg), ov = sigm(go);
        float cn = fv * cst[j] + iv * gv;
        float hn = ov * tanh_(cn);
        if (act) { cst[j] = cn; hst[j] = hn; }
        outv[j] = act ? hn : 0.0f;
      }
      __builtin_nontemporal_store(outv,
          (f32x4*)&out[((size_t)bglob * TT + t) * HH + ig * NE + e4]);
      u32x4 pub;
      pub[0] = (u32)f2bf(hst[0]) | ((u32)f2bf(hst[1]) << 16);
      pub[1] = (u32)(t + 1);
      pub[2] = (u32)f2bf(hst[2]) | ((u32)f2bf(hst[3]) << 16);
      pub[3] = (u32)(t + 1);
      u64 pa = hb + (u64)((size_t)(slot ^ 1) * BB * 128 * 16) + pub_off;
      asm volatile("global_store_dwordx4 %0, %1, off sc1"
                   :: "v"(pa), "v"(pub) : "memory");
    }
    // no post-cell barrier: stage(t+1) hA writes are ordered after every
    // wave's MFMA(t) hA reads by the post-MFMA barrier; gates_s overwrite
    // by MFMA(t+1) is ordered after cell(t) reads by the post-stage barrier.
  }

  // sync-free zero-fill for t >= gmax (h frozen, outputs are PAD_VALUE=0)
  {
    f32x4 z = {0.f, 0.f, 0.f, 0.f};
    for (int t = gmax; t < TT; ++t)
      __builtin_nontemporal_store(z,
          (f32x4*)&out[((size_t)bglob * TT + t) * HH + ig * NE + e4]);
  }

  // finals: h_T, c_T (fp32), 4 elems per thread
  {
    f32x4 hv, cv;
#pragma unroll
    for (int j = 0; j < 4; j++) { hv[j] = hst[j]; cv[j] = cst[j]; }
    *(f32x4*)&out[(size_t)BB * TT * HH + (size_t)bglob * HH + ig * NE + e4] = hv;
    *(f32x4*)&out[(size_t)BB * TT * HH + (size_t)BB * HH + (size_t)bglob * HH + ig * NE + e4] = cv;
  }
}

extern "C" void kernel_launch(void* const* d_in, const int* in_sizes, int n_in,
                              void* d_out, int out_size, void* d_ws, size_t ws_size,
                              hipStream_t stream) {
  const int*   x     = (const int*)d_in[0];
  const int*   x_len = (const int*)d_in[1];
  const float* W_ih  = (const float*)d_in[2];
  const float* W_hh  = (const float*)d_in[3];
  const float* b_ih  = (const float*)d_in[4];
  const float* b_hh  = (const float*)d_in[5];
  float* out = (float*)d_out;

  char* ws = (char*)d_ws;
  u8*  x_t  = (u8*)ws;                      // 131072 B
  u32* hbuf = (u32*)(ws + 131072);          // 524288 B (2 slots x 128 x 128 x 16B)

  lstm_init<<<512, 256, 0, stream>>>(x, x_t, hbuf);
  lstm_persist<<<64, 256, 0, stream>>>(x_t, x_len, W_ih, W_hh, b_ih, b_hh, out, hbuf);
}